// Round 3
// baseline (1217.235 us; speedup 1.0000x reference)
//
#include <hip/hip_runtime.h>

#define T_STEPS 500
#define N_NEUR  256
#define N_IN    256
#define N_BATCH 128

// Bs gap swizzle: insert a 4-float gap every 16 floats. Keeps any aligned
// 8-float block contiguous (so float4/b128 ops still work) while spreading
// the 16 lanes' 32B-strided reads across banks (<=2-way, which is free).
#define BPOS(c) ((c) + (((c) >> 4) << 2))

// ---------------------------------------------------------------------------
// Kernel 1 (v3): XW = X @ W_in  (M=64000, K=256, N=256), fp32 vector GEMM.
// 128x128 tile, 8x8 acc/thread. Changes vs v2 (bit-identical arithmetic):
//  - next k0-tile is loaded into registers AFTER the store barrier, so the
//    global-load latency (and the __syncthreads vmcnt drain) hides under the
//    ~2000-cycle compute phase instead of serializing with it.
//  - Bs uses BPOS gap swizzle: the b-fragment reads were a 4-way bank
//    conflict (16 lanes at 32B stride); now <=2-way (free).
// Per-output accumulation order is unchanged -> bit-identical C.
// ---------------------------------------------------------------------------
__global__ __launch_bounds__(256, 4) void xw_gemm3_kernel(
    const float* __restrict__ A,   // [M,256]
    const float* __restrict__ W,   // [256,256]
    float* __restrict__ C)         // [M,256]
{
    __shared__ float As[16][132];
    __shared__ float Bs[16][160];   // BPOS(127)=155 max read extent, pad to 160
    const int tid = threadIdx.x;
    const int bm  = blockIdx.x;    // 0..499
    const int bn  = blockIdx.y;    // 0..1
    const int ty  = tid >> 4;      // 0..15
    const int tx  = tid & 15;      // 0..15
    const int arow  = tid >> 1;          // 0..127
    const int akoff = (tid & 1) * 8;     // 0 or 8
    const int brow  = tid >> 4;          // 0..15
    const int bcol  = (tid & 15) * 8;    // 0..120
    const float* Ab = A + (size_t)bm * 128 * 256;

    float acc[8][8];
#pragma unroll
    for (int i = 0; i < 8; ++i)
#pragma unroll
        for (int j = 0; j < 8; ++j) acc[i][j] = 0.f;

    // prologue: k0 = 0 tile into registers
    float4 av0 = *(const float4*)(Ab + (size_t)arow * 256 + akoff);
    float4 av1 = *(const float4*)(Ab + (size_t)arow * 256 + akoff + 4);
    float4 bv0 = *(const float4*)(W + (size_t)brow * 256 + bn * 128 + bcol);
    float4 bv1 = *(const float4*)(W + (size_t)brow * 256 + bn * 128 + bcol + 4);

    for (int k0 = 0; k0 < 256; k0 += 16) {
        __syncthreads();                      // prev compute done (no-op @k0=0)
        As[akoff + 0][arow] = av0.x; As[akoff + 1][arow] = av0.y;
        As[akoff + 2][arow] = av0.z; As[akoff + 3][arow] = av0.w;
        As[akoff + 4][arow] = av1.x; As[akoff + 5][arow] = av1.y;
        As[akoff + 6][arow] = av1.z; As[akoff + 7][arow] = av1.w;
        *(float4*)&Bs[brow][BPOS(bcol)]     = bv0;
        *(float4*)&Bs[brow][BPOS(bcol) + 4] = bv1;
        __syncthreads();
        if (k0 + 16 < 256) {                  // prefetch next tile into regs
            av0 = *(const float4*)(Ab + (size_t)arow * 256 + k0 + 16 + akoff);
            av1 = *(const float4*)(Ab + (size_t)arow * 256 + k0 + 16 + akoff + 4);
            bv0 = *(const float4*)(W + (size_t)(k0 + 16 + brow) * 256 + bn * 128 + bcol);
            bv1 = *(const float4*)(W + (size_t)(k0 + 16 + brow) * 256 + bn * 128 + bcol + 4);
        }
#pragma unroll
        for (int kk = 0; kk < 16; ++kk) {
            float a[8], b[8];
#pragma unroll
            for (int i = 0; i < 8; ++i) a[i] = As[kk][ty * 8 + i];
#pragma unroll
            for (int j = 0; j < 8; ++j) b[j] = Bs[kk][BPOS(tx * 8) + j];
#pragma unroll
            for (int i = 0; i < 8; ++i)
#pragma unroll
                for (int j = 0; j < 8; ++j)
                    acc[i][j] += a[i] * b[j];
        }
    }
    const int crow = bm * 128 + ty * 8;
    const int ccol = bn * 128 + tx * 8;
#pragma unroll
    for (int i = 0; i < 8; ++i) {
        float4 v0 = make_float4(acc[i][0], acc[i][1], acc[i][2], acc[i][3]);
        float4 v1 = make_float4(acc[i][4], acc[i][5], acc[i][6], acc[i][7]);
        *(float4*)(C + (size_t)(crow + i) * 256 + ccol)     = v0;
        *(float4*)(C + (size_t)(crow + i) * 256 + ccol + 4) = v1;
    }
}

// ---------------------------------------------------------------------------
// Kernel 1b: build wrec_z = w_rec with zeroed diagonal + zero sentinel row 256.
// ---------------------------------------------------------------------------
__global__ void prep_wrec_kernel(const float* __restrict__ w_rec,
                                 float* __restrict__ wz)
{
    int i = blockIdx.x * 256 + threadIdx.x;   // 0 .. 257*256-1
    if (i < 256 * 256) {
        int r = i >> 8, c = i & 255;
        wz[i] = (r == c) ? 0.f : w_rec[i];
    } else {
        wz[i] = 0.f;                           // sentinel row 256
    }
}

__device__ __forceinline__ unsigned long long rfl64(unsigned long long q) {
    unsigned hi = (unsigned)__builtin_amdgcn_readfirstlane((int)(q >> 32));
    unsigned lo = (unsigned)__builtin_amdgcn_readfirstlane((int)(unsigned)q);
    return ((unsigned long long)hi << 32) | (unsigned long long)lo;
}

// ---------------------------------------------------------------------------
// Kernel 2 (v6): sparse scalar-mask scan = R0's scan2 structure (256 threads,
// thread n = neuron n; whole-block i_rec per thread; NO partial exchange)
// with two scheduling fixes:
//  - loop barriers are raw s_barrier + s_waitcnt lgkmcnt(0): only the LDS
//    mask handoff is ordered; the 4 nontemporal HBM stores and the xw
//    prefetch are NOT drained every step (the implicit vmcnt(0) drain in
//    __syncthreads was ~70% of scan2/3/4's per-step time).
//  - xw prefetch is 2 steps deep so its HBM latency spans two steps.
// i_rec chunk/sentinel arithmetic + dynamics are copied verbatim from the
// harness-passing scan2 -> bit-identical trajectory.
// ---------------------------------------------------------------------------
__global__ __launch_bounds__(256) void lsnn_scan6_kernel(
    const float* __restrict__ xw,    // [B,T,N]
    const float* __restrict__ wz,    // [257,256] diag-zeroed + zero row
    const float* __restrict__ z0, const float* __restrict__ v0,
    const float* __restrict__ a0, const float* __restrict__ lsd0,
    float* __restrict__ out)         // [4,T,B,N]
{
    const int b    = blockIdx.x;
    const int n    = threadIdx.x;
    const int lane = n & 63;
    const int wid  = n >> 6;

    __shared__ __align__(16) unsigned long long msk[2][4];

    const float dv   = (float)0.9512294245007140018;  // exp(-1/20) fp32
    const float omdv = 1.0f - dv;

    const int bn = b * N_NEUR + n;
    float z   = z0[bn];
    float v   = v0[bn];
    float a   = a0[bn];
    float lsd = lsd0[bn];

    {
        unsigned long long wm = __ballot(z != 0.f);
        if (lane == 0) msk[0][wid] = wm;
    }
    __syncthreads();

    // 2-deep xw prefetch
    float x1 = xw[((size_t)b * T_STEPS) * N_NEUR + n];
    float x2 = xw[((size_t)b * T_STEPS + (T_STEPS > 1 ? 1 : 0)) * N_NEUR + n];
    const size_t PL = (size_t)T_STEPS * N_BATCH * N_NEUR;

    for (int t = 0; t < T_STEPS; ++t) {
        float x_cur = x1;
        x1 = x2;
        {
            int tn = (t + 2 < T_STEPS) ? t + 2 : T_STEPS - 1;
            x2 = xw[((size_t)b * T_STEPS + tn) * N_NEUR + n];
        }

        const int rb = t & 1;
        // ---- pull the 4 wave masks into scalar registers ------------------
        unsigned long long m0 = rfl64(msk[rb][0]);
        unsigned long long m1 = rfl64(msk[rb][1]);
        unsigned long long m2 = rfl64(msk[rb][2]);
        unsigned long long m3 = rfl64(msk[rb][3]);

        const int c0 = __popcll(m0), c1 = __popcll(m1);
        const int c2 = __popcll(m2), c3 = __popcll(m3);
        const int mx = max(max(c0, c1), max(c2, c3));

        // ---- gather: 32 loads in flight per iteration (verbatim scan2) ----
        float p0 = 0.f, p1 = 0.f, p2 = 0.f, p3 = 0.f;
        for (int i0 = 0; i0 < mx; i0 += 8) {
            int id0[8], id1[8], id2[8], id3[8];
#pragma unroll
            for (int j = 0; j < 8; ++j) {
                id0[j] = m0 ? (__builtin_ctzll(m0) + 0)   : 256;  m0 &= m0 - 1;
                id1[j] = m1 ? (__builtin_ctzll(m1) + 64)  : 256;  m1 &= m1 - 1;
                id2[j] = m2 ? (__builtin_ctzll(m2) + 128) : 256;  m2 &= m2 - 1;
                id3[j] = m3 ? (__builtin_ctzll(m3) + 192) : 256;  m3 &= m3 - 1;
            }
            float w0[8], w1[8], w2[8], w3[8];
#pragma unroll
            for (int j = 0; j < 8; ++j) {
                w0[j] = wz[id0[j] * N_NEUR + n];
                w1[j] = wz[id1[j] * N_NEUR + n];
                w2[j] = wz[id2[j] * N_NEUR + n];
                w3[j] = wz[id3[j] * N_NEUR + n];
            }
#pragma unroll
            for (int j = 0; j < 8; ++j) {
                p0 += w0[j]; p1 += w1[j]; p2 += w2[j]; p3 += w3[j];
            }
        }
        float i_rec = ((p0 + p1) + p2) + p3;

        // ---- neuron dynamics (verbatim) -----------------------------------
        float i_in  = x_cur + i_rec;              // INTERNAL_CURRENT == 0
        float new_a = dv * a + omdv * z;
        float thr   = 0.03f + new_a * 1.8f;
        float new_v = dv * v + omdv * i_in - thr * z;
        float v_sc  = (new_v - thr) / thr;
        float zs    = (v_sc > 0.f) ? 1.f : 0.f;
        zs          = (lsd >= 2.0f) ? zs : 0.f;
        float new_lsd = (lsd + 1.f) * (1.f - zs);

        // ---- emit (z, v, thr, v_sc), streaming stores (never drained) -----
        size_t o = (size_t)t * (N_BATCH * N_NEUR) + (size_t)b * N_NEUR + n;
        __builtin_nontemporal_store(zs,    out + o);
        __builtin_nontemporal_store(new_v, out + o + PL);
        __builtin_nontemporal_store(thr,   out + o + 2 * PL);
        __builtin_nontemporal_store(v_sc,  out + o + 3 * PL);

        v = new_v; a = new_a; lsd = new_lsd; z = zs;

        // ---- publish next-step masks; raw barrier (LDS-only ordering) -----
        {
            unsigned long long wm = __ballot(zs != 0.f);
            if (lane == 0) msk[rb ^ 1][wid] = wm;
        }
        asm volatile("s_waitcnt lgkmcnt(0)" ::: "memory");
        __builtin_amdgcn_s_barrier();
        asm volatile("" ::: "memory");
    }
}

// ---------------------------------------------------------------------------
// Fallback scan (R1 version) — used only if ws_size is too small.
// ---------------------------------------------------------------------------
template <bool USE_XW>
__global__ __launch_bounds__(256) void lsnn_scan_kernel(
    const float* __restrict__ xin,
    const float* __restrict__ w_in,
    const float* __restrict__ w_rec,
    const float* __restrict__ z0, const float* __restrict__ v0,
    const float* __restrict__ a0, const float* __restrict__ lsd0,
    float* __restrict__ out)
{
    const int b    = blockIdx.x;
    const int n    = threadIdx.x;
    const int lane = n & 63;
    const int wid  = n >> 6;

    __shared__ int   cnt4[4];
    __shared__ int   act[256];
    __shared__ float xsh[256];

    const float dv   = (float)0.9512294245007140018;
    const float omdv = 1.0f - dv;

    const int base_bn = b * N_NEUR + n;
    float z   = z0[base_bn];
    float v   = v0[base_bn];
    float a   = a0[base_bn];
    float lsd = lsd0[base_bn];

    act[n] = 0;
    {
        unsigned long long wm = __ballot(z != 0.f);
        if (lane == 0) cnt4[wid] = __popcll(wm);
        if (z != 0.f) {
            int pos = __popcll(wm & ((1ull << lane) - 1ull));
            act[wid * 64 + pos] = n;
        }
        if (!USE_XW) xsh[n] = xin[((size_t)b * T_STEPS) * N_IN + n];
    }
    __syncthreads();

    float x_next = USE_XW ? xin[((size_t)b * T_STEPS) * N_NEUR + n] : 0.f;

    for (int t = 0; t < T_STEPS; ++t) {
        float x_cur = x_next;
        if (USE_XW) {
            int tn = (t + 1 < T_STEPS) ? t + 1 : t;
            x_next = xin[((size_t)b * T_STEPS + tn) * N_NEUR + n];
        }
        const int cs0 = cnt4[0], cs1 = cnt4[1], cs2 = cnt4[2], cs3 = cnt4[3];
        int mx = max(max(cs0, cs1), max(cs2, cs3));
        float r0 = 0.f, r1 = 0.f, r2 = 0.f, r3 = 0.f;
        for (int i0 = 0; i0 < mx; i0 += 8) {
            float wv[4][8];
            bool  ok[4][8];
#pragma unroll
            for (int sgi = 0; sgi < 4; ++sgi) {
                const int cs = (sgi == 0) ? cs0 : (sgi == 1) ? cs1 : (sgi == 2) ? cs2 : cs3;
#pragma unroll
                for (int j = 0; j < 8; ++j) {
                    int ii = i0 + j;
                    int m  = act[sgi * 64 + (ii < cs ? ii : 0)] & 255;
                    wv[sgi][j] = w_rec[m * N_NEUR + n];
                    ok[sgi][j] = (ii < cs) && (m != n);
                }
            }
#pragma unroll
            for (int j = 0; j < 8; ++j) r0 += ok[0][j] ? wv[0][j] : 0.f;
#pragma unroll
            for (int j = 0; j < 8; ++j) r1 += ok[1][j] ? wv[1][j] : 0.f;
#pragma unroll
            for (int j = 0; j < 8; ++j) r2 += ok[2][j] ? wv[2][j] : 0.f;
#pragma unroll
            for (int j = 0; j < 8; ++j) r3 += ok[3][j] ? wv[3][j] : 0.f;
        }
        float i_rec = ((r0 + r1) + r2) + r3;

        float xdot;
        if (USE_XW) {
            xdot = x_cur;
        } else {
            float sum = 0.f;
#pragma unroll 8
            for (int m = 0; m < N_IN; ++m) sum += xsh[m] * w_in[m * N_NEUR + n];
            xdot = sum;
        }
        float i_in = xdot + i_rec;

        float new_a = dv * a + omdv * z;
        float thr   = 0.03f + new_a * 1.8f;
        float new_v = dv * v + omdv * i_in - thr * z;
        float v_sc  = (new_v - thr) / thr;
        float zs    = (v_sc > 0.f) ? 1.f : 0.f;
        zs          = (lsd >= 2.0f) ? zs : 0.f;
        float new_lsd = (lsd + 1.f) * (1.f - zs);

        const size_t PL = (size_t)T_STEPS * N_BATCH * N_NEUR;
        size_t o = (size_t)t * (N_BATCH * N_NEUR) + (size_t)b * N_NEUR + n;
        out[o]          = zs;
        out[o + PL]     = new_v;
        out[o + 2 * PL] = thr;
        out[o + 3 * PL] = v_sc;

        v = new_v; a = new_a; lsd = new_lsd; z = zs;

        __syncthreads();
        unsigned long long wm = __ballot(zs != 0.f);
        if (lane == 0) cnt4[wid] = __popcll(wm);
        if (zs != 0.f) {
            int pos = __popcll(wm & ((1ull << lane) - 1ull));
            act[wid * 64 + pos] = n;
        }
        if (!USE_XW && (t + 1 < T_STEPS))
            xsh[n] = xin[((size_t)b * T_STEPS + t + 1) * N_IN + n];
        __syncthreads();
    }
}

// ---------------------------------------------------------------------------
extern "C" void kernel_launch(void* const* d_in, const int* in_sizes, int n_in,
                              void* d_out, int out_size, void* d_ws, size_t ws_size,
                              hipStream_t stream) {
    const float* x     = (const float*)d_in[0];
    const float* w_in  = (const float*)d_in[1];
    const float* w_rec = (const float*)d_in[2];
    const float* z0    = (const float*)d_in[3];
    const float* v0    = (const float*)d_in[4];
    const float* a0    = (const float*)d_in[5];
    const float* lsd0  = (const float*)d_in[6];
    float* out = (float*)d_out;

    const size_t xw_bytes = (size_t)N_BATCH * T_STEPS * N_NEUR * sizeof(float);
    const size_t wz_bytes = (size_t)257 * 256 * sizeof(float);

    if (ws_size >= xw_bytes + wz_bytes) {
        float* xw = (float*)d_ws;
        float* wz = (float*)((char*)d_ws + xw_bytes);
        prep_wrec_kernel<<<257, 256, 0, stream>>>(w_rec, wz);
        dim3 grid(500, 2, 1);
        xw_gemm3_kernel<<<grid, 256, 0, stream>>>(x, w_in, xw);
        lsnn_scan6_kernel<<<N_BATCH, 256, 0, stream>>>(
            xw, wz, z0, v0, a0, lsd0, out);
    } else if (ws_size >= xw_bytes) {
        float* xw = (float*)d_ws;
        dim3 grid(500, 2, 1);
        xw_gemm3_kernel<<<grid, 256, 0, stream>>>(x, w_in, xw);
        lsnn_scan_kernel<true><<<N_BATCH, 256, 0, stream>>>(
            xw, nullptr, w_rec, z0, v0, a0, lsd0, out);
    } else {
        lsnn_scan_kernel<false><<<N_BATCH, 256, 0, stream>>>(
            x, w_in, w_rec, z0, v0, a0, lsd0, out);
    }
}

// Round 4
// 939.893 us; speedup vs baseline: 1.2951x; 1.2951x over previous
//
#include <hip/hip_runtime.h>

#define T_STEPS 500
#define N_NEUR  256
#define N_IN    256
#define N_BATCH 128
#define CH      32      // xw LDS staging chunk (steps)

// Bs gap swizzle: insert a 4-float gap every 16 floats. Keeps any aligned
// 8-float block contiguous (float4/b128 still work) while spreading the 16
// lanes' 32B-strided reads across banks (<=2-way, which is free).
#define BPOS(c) ((c) + (((c) >> 4) << 2))

// ---------------------------------------------------------------------------
// Kernel 1 (v4): XW = X @ W_in  (M=64000, K=256, N=256), fp32 vector GEMM.
// = R3's gemm3 structure (prefetch-into-regs after the store barrier, BPOS
// bank swizzle) WITHOUT the __launch_bounds__(256,4) occupancy cap that
// forced a 128-VGPR budget and (theory) spilled the 8x8 accumulator.
// Per-output accumulation order unchanged -> bit-identical C.
// ---------------------------------------------------------------------------
__global__ __launch_bounds__(256) void xw_gemm4_kernel(
    const float* __restrict__ A,   // [M,256]
    const float* __restrict__ W,   // [256,256]
    float* __restrict__ C)         // [M,256]
{
    __shared__ float As[16][132];
    __shared__ float Bs[16][160];   // BPOS(127)=155 max extent, pad to 160
    const int tid = threadIdx.x;
    const int bm  = blockIdx.x;    // 0..499
    const int bn  = blockIdx.y;    // 0..1
    const int ty  = tid >> 4;      // 0..15
    const int tx  = tid & 15;      // 0..15
    const int arow  = tid >> 1;          // 0..127
    const int akoff = (tid & 1) * 8;     // 0 or 8
    const int brow  = tid >> 4;          // 0..15
    const int bcol  = (tid & 15) * 8;    // 0..120
    const float* Ab = A + (size_t)bm * 128 * 256;

    float acc[8][8];
#pragma unroll
    for (int i = 0; i < 8; ++i)
#pragma unroll
        for (int j = 0; j < 8; ++j) acc[i][j] = 0.f;

    // prologue: k0 = 0 tile into registers
    float4 av0 = *(const float4*)(Ab + (size_t)arow * 256 + akoff);
    float4 av1 = *(const float4*)(Ab + (size_t)arow * 256 + akoff + 4);
    float4 bv0 = *(const float4*)(W + (size_t)brow * 256 + bn * 128 + bcol);
    float4 bv1 = *(const float4*)(W + (size_t)brow * 256 + bn * 128 + bcol + 4);

    for (int k0 = 0; k0 < 256; k0 += 16) {
        __syncthreads();                      // prev compute done (no-op @k0=0)
        As[akoff + 0][arow] = av0.x; As[akoff + 1][arow] = av0.y;
        As[akoff + 2][arow] = av0.z; As[akoff + 3][arow] = av0.w;
        As[akoff + 4][arow] = av1.x; As[akoff + 5][arow] = av1.y;
        As[akoff + 6][arow] = av1.z; As[akoff + 7][arow] = av1.w;
        *(float4*)&Bs[brow][BPOS(bcol)]     = bv0;
        *(float4*)&Bs[brow][BPOS(bcol) + 4] = bv1;
        __syncthreads();
        if (k0 + 16 < 256) {                  // prefetch next tile into regs
            av0 = *(const float4*)(Ab + (size_t)arow * 256 + k0 + 16 + akoff);
            av1 = *(const float4*)(Ab + (size_t)arow * 256 + k0 + 16 + akoff + 4);
            bv0 = *(const float4*)(W + (size_t)(k0 + 16 + brow) * 256 + bn * 128 + bcol);
            bv1 = *(const float4*)(W + (size_t)(k0 + 16 + brow) * 256 + bn * 128 + bcol + 4);
        }
#pragma unroll
        for (int kk = 0; kk < 16; ++kk) {
            float a[8], b[8];
#pragma unroll
            for (int i = 0; i < 8; ++i) a[i] = As[kk][ty * 8 + i];
#pragma unroll
            for (int j = 0; j < 8; ++j) b[j] = Bs[kk][BPOS(tx * 8) + j];
#pragma unroll
            for (int i = 0; i < 8; ++i)
#pragma unroll
                for (int j = 0; j < 8; ++j)
                    acc[i][j] += a[i] * b[j];
        }
    }
    const int crow = bm * 128 + ty * 8;
    const int ccol = bn * 128 + tx * 8;
#pragma unroll
    for (int i = 0; i < 8; ++i) {
        float4 v0 = make_float4(acc[i][0], acc[i][1], acc[i][2], acc[i][3]);
        float4 v1 = make_float4(acc[i][4], acc[i][5], acc[i][6], acc[i][7]);
        *(float4*)(C + (size_t)(crow + i) * 256 + ccol)     = v0;
        *(float4*)(C + (size_t)(crow + i) * 256 + ccol + 4) = v1;
    }
}

// ---------------------------------------------------------------------------
// Kernel 1b: build wrec_z = w_rec with zeroed diagonal + zero sentinel row 256.
// ---------------------------------------------------------------------------
__global__ void prep_wrec_kernel(const float* __restrict__ w_rec,
                                 float* __restrict__ wz)
{
    int i = blockIdx.x * 256 + threadIdx.x;   // 0 .. 257*256-1
    if (i < 256 * 256) {
        int r = i >> 8, c = i & 255;
        wz[i] = (r == c) ? 0.f : w_rec[i];
    } else {
        wz[i] = 0.f;                           // sentinel row 256
    }
}

__device__ __forceinline__ unsigned long long rfl64(unsigned long long q) {
    unsigned hi = (unsigned)__builtin_amdgcn_readfirstlane((int)(q >> 32));
    unsigned lo = (unsigned)__builtin_amdgcn_readfirstlane((int)(unsigned)q);
    return ((unsigned long long)hi << 32) | (unsigned long long)lo;
}

// ---------------------------------------------------------------------------
// Kernel 2 (v7): sparse scalar-mask scan with a CLEAN per-step vmem chain.
//
// vmcnt retires IN ORDER, so consuming the gather results (newest vmem ops)
// drains every older outstanding op. scan2/6 paid ~1400 cyc/step draining the
// per-step HBM xw prefetch and the nontemporal-store acks. v7 removes both:
//  - xw is staged into LDS in 32-step chunks (double-buffered, 64 KB); the
//    per-step x read is a ds_read (lgkm pipe, overlaps the mask read). The
//    staging's HBM latency is paid once per 32 steps, off the steady chain.
//  - outputs are held in registers one step and written with PLAIN stores at
//    the TOP of the next iteration: their L2-ack (~200cy) is covered by the
//    mask-walk before the gather wait. (NT stores ack from HBM -> slow.)
// i_rec walk/sentinel arithmetic + dynamics are verbatim scan2 -> the
// trajectory and all stored values are bit-identical.
// ---------------------------------------------------------------------------
__global__ __launch_bounds__(256) void lsnn_scan7_kernel(
    const float* __restrict__ xw,    // [B,T,N]
    const float* __restrict__ wz,    // [257,256] diag-zeroed + zero row
    const float* __restrict__ z0, const float* __restrict__ v0,
    const float* __restrict__ a0, const float* __restrict__ lsd0,
    float* __restrict__ out)         // [4,T,B,N]
{
    const int b    = blockIdx.x;
    const int n    = threadIdx.x;
    const int lane = n & 63;
    const int wid  = n >> 6;

    __shared__ __align__(16) float xbuf[2][CH * N_NEUR];   // 64 KB
    __shared__ __align__(16) unsigned long long msk[2][4];

    const float dv   = (float)0.9512294245007140018;  // exp(-1/20) fp32
    const float omdv = 1.0f - dv;

    const int bn = b * N_NEUR + n;
    float z   = z0[bn];
    float v   = v0[bn];
    float a   = a0[bn];
    float lsd = lsd0[bn];

    {
        unsigned long long wm = __ballot(z != 0.f);
        if (lane == 0) msk[0][wid] = wm;
    }

    // ---- prologue: stage chunk 0 (steps 0..31) into xbuf[0] ---------------
    const float* xb = xw + (size_t)b * T_STEPS * N_NEUR;
    {
#pragma unroll
        for (int i = 0; i < 8; ++i) {
            int r = wid * 8 + i;                       // row < 32 < 500
            float4 v4 = *(const float4*)(xb + (size_t)r * N_NEUR + lane * 4);
            *(float4*)&xbuf[0][r * N_NEUR + lane * 4] = v4;
        }
    }
    __syncthreads();

    const size_t PL = (size_t)T_STEPS * N_BATCH * N_NEUR;
    float zs_p = 0.f, v_p = 0.f, thr_p = 0.f, vsc_p = 0.f;  // pending outputs

    for (int t = 0; t < T_STEPS; ++t) {
        const int rb = t & 1;

        // ---- top: mask + x reads (lgkm), then prev-step stores (L2-ack) ---
        unsigned long long m0 = rfl64(msk[rb][0]);
        unsigned long long m1 = rfl64(msk[rb][1]);
        unsigned long long m2 = rfl64(msk[rb][2]);
        unsigned long long m3 = rfl64(msk[rb][3]);
        float x_cur = xbuf[(t >> 5) & 1][(t & 31) * N_NEUR + n];

        if (t > 0) {
            size_t op = (size_t)(t - 1) * (N_BATCH * N_NEUR) + (size_t)b * N_NEUR + n;
            out[op]          = zs_p;
            out[op + PL]     = v_p;
            out[op + 2 * PL] = thr_p;
            out[op + 3 * PL] = vsc_p;
        }

        const int c0 = __popcll(m0), c1 = __popcll(m1);
        const int c2 = __popcll(m2), c3 = __popcll(m3);
        const int mx = max(max(c0, c1), max(c2, c3));

        // ---- gather: 32 loads in flight per iteration (verbatim scan2) ----
        float p0 = 0.f, p1 = 0.f, p2 = 0.f, p3 = 0.f;
        for (int i0 = 0; i0 < mx; i0 += 8) {
            int id0[8], id1[8], id2[8], id3[8];
#pragma unroll
            for (int j = 0; j < 8; ++j) {
                id0[j] = m0 ? (__builtin_ctzll(m0) + 0)   : 256;  m0 &= m0 - 1;
                id1[j] = m1 ? (__builtin_ctzll(m1) + 64)  : 256;  m1 &= m1 - 1;
                id2[j] = m2 ? (__builtin_ctzll(m2) + 128) : 256;  m2 &= m2 - 1;
                id3[j] = m3 ? (__builtin_ctzll(m3) + 192) : 256;  m3 &= m3 - 1;
            }
            float w0[8], w1[8], w2[8], w3[8];
#pragma unroll
            for (int j = 0; j < 8; ++j) {
                w0[j] = wz[id0[j] * N_NEUR + n];
                w1[j] = wz[id1[j] * N_NEUR + n];
                w2[j] = wz[id2[j] * N_NEUR + n];
                w3[j] = wz[id3[j] * N_NEUR + n];
            }
#pragma unroll
            for (int j = 0; j < 8; ++j) {
                p0 += w0[j]; p1 += w1[j]; p2 += w2[j]; p3 += w3[j];
            }
        }
        float i_rec = ((p0 + p1) + p2) + p3;

        // ---- neuron dynamics (verbatim) -----------------------------------
        float i_in  = x_cur + i_rec;              // INTERNAL_CURRENT == 0
        float new_a = dv * a + omdv * z;
        float thr   = 0.03f + new_a * 1.8f;
        float new_v = dv * v + omdv * i_in - thr * z;
        float v_sc  = (new_v - thr) / thr;
        float zs    = (v_sc > 0.f) ? 1.f : 0.f;
        zs          = (lsd >= 2.0f) ? zs : 0.f;
        float new_lsd = (lsd + 1.f) * (1.f - zs);

        // hold outputs one step (stored at next iteration's top)
        zs_p = zs; v_p = new_v; thr_p = thr; vsc_p = v_sc;
        v = new_v; a = new_a; lsd = new_lsd; z = zs;

        // ---- chunk staging: once per 32 steps, off the steady chain -------
        if ((t & 31) == 0 && t + CH < T_STEPS) {
            const int t0n  = t + CH;
            const int rows = (T_STEPS - t0n < CH) ? (T_STEPS - t0n) : CH;
            const int par  = ((t >> 5) + 1) & 1;
#pragma unroll
            for (int i = 0; i < 8; ++i) {
                int r = wid * 8 + i;
                if (r < rows) {
                    float4 v4 = *(const float4*)(xb + (size_t)(t0n + r) * N_NEUR + lane * 4);
                    *(float4*)&xbuf[par][r * N_NEUR + lane * 4] = v4;
                }
            }
        }

        // ---- publish next-step masks; LDS-only barrier --------------------
        {
            unsigned long long wm = __ballot(zs != 0.f);
            if (lane == 0) msk[rb ^ 1][wid] = wm;
        }
        asm volatile("s_waitcnt lgkmcnt(0)" ::: "memory");
        __builtin_amdgcn_s_barrier();
        asm volatile("" ::: "memory");
    }

    // ---- epilogue: store step T-1 outputs ---------------------------------
    {
        size_t op = (size_t)(T_STEPS - 1) * (N_BATCH * N_NEUR) + (size_t)b * N_NEUR + n;
        out[op]          = zs_p;
        out[op + PL]     = v_p;
        out[op + 2 * PL] = thr_p;
        out[op + 3 * PL] = vsc_p;
    }
}

// ---------------------------------------------------------------------------
// Fallback scan (R1 version) — used only if ws_size is too small.
// ---------------------------------------------------------------------------
template <bool USE_XW>
__global__ __launch_bounds__(256) void lsnn_scan_kernel(
    const float* __restrict__ xin,
    const float* __restrict__ w_in,
    const float* __restrict__ w_rec,
    const float* __restrict__ z0, const float* __restrict__ v0,
    const float* __restrict__ a0, const float* __restrict__ lsd0,
    float* __restrict__ out)
{
    const int b    = blockIdx.x;
    const int n    = threadIdx.x;
    const int lane = n & 63;
    const int wid  = n >> 6;

    __shared__ int   cnt4[4];
    __shared__ int   act[256];
    __shared__ float xsh[256];

    const float dv   = (float)0.9512294245007140018;
    const float omdv = 1.0f - dv;

    const int base_bn = b * N_NEUR + n;
    float z   = z0[base_bn];
    float v   = v0[base_bn];
    float a   = a0[base_bn];
    float lsd = lsd0[base_bn];

    act[n] = 0;
    {
        unsigned long long wm = __ballot(z != 0.f);
        if (lane == 0) cnt4[wid] = __popcll(wm);
        if (z != 0.f) {
            int pos = __popcll(wm & ((1ull << lane) - 1ull));
            act[wid * 64 + pos] = n;
        }
        if (!USE_XW) xsh[n] = xin[((size_t)b * T_STEPS) * N_IN + n];
    }
    __syncthreads();

    float x_next = USE_XW ? xin[((size_t)b * T_STEPS) * N_NEUR + n] : 0.f;

    for (int t = 0; t < T_STEPS; ++t) {
        float x_cur = x_next;
        if (USE_XW) {
            int tn = (t + 1 < T_STEPS) ? t + 1 : t;
            x_next = xin[((size_t)b * T_STEPS + tn) * N_NEUR + n];
        }
        const int cs0 = cnt4[0], cs1 = cnt4[1], cs2 = cnt4[2], cs3 = cnt4[3];
        int mx = max(max(cs0, cs1), max(cs2, cs3));
        float r0 = 0.f, r1 = 0.f, r2 = 0.f, r3 = 0.f;
        for (int i0 = 0; i0 < mx; i0 += 8) {
            float wv[4][8];
            bool  ok[4][8];
#pragma unroll
            for (int sgi = 0; sgi < 4; ++sgi) {
                const int cs = (sgi == 0) ? cs0 : (sgi == 1) ? cs1 : (sgi == 2) ? cs2 : cs3;
#pragma unroll
                for (int j = 0; j < 8; ++j) {
                    int ii = i0 + j;
                    int m  = act[sgi * 64 + (ii < cs ? ii : 0)] & 255;
                    wv[sgi][j] = w_rec[m * N_NEUR + n];
                    ok[sgi][j] = (ii < cs) && (m != n);
                }
            }
#pragma unroll
            for (int j = 0; j < 8; ++j) r0 += ok[0][j] ? wv[0][j] : 0.f;
#pragma unroll
            for (int j = 0; j < 8; ++j) r1 += ok[1][j] ? wv[1][j] : 0.f;
#pragma unroll
            for (int j = 0; j < 8; ++j) r2 += ok[2][j] ? wv[2][j] : 0.f;
#pragma unroll
            for (int j = 0; j < 8; ++j) r3 += ok[3][j] ? wv[3][j] : 0.f;
        }
        float i_rec = ((r0 + r1) + r2) + r3;

        float xdot;
        if (USE_XW) {
            xdot = x_cur;
        } else {
            float sum = 0.f;
#pragma unroll 8
            for (int m = 0; m < N_IN; ++m) sum += xsh[m] * w_in[m * N_NEUR + n];
            xdot = sum;
        }
        float i_in = xdot + i_rec;

        float new_a = dv * a + omdv * z;
        float thr   = 0.03f + new_a * 1.8f;
        float new_v = dv * v + omdv * i_in - thr * z;
        float v_sc  = (new_v - thr) / thr;
        float zs    = (v_sc > 0.f) ? 1.f : 0.f;
        zs          = (lsd >= 2.0f) ? zs : 0.f;
        float new_lsd = (lsd + 1.f) * (1.f - zs);

        const size_t PL = (size_t)T_STEPS * N_BATCH * N_NEUR;
        size_t o = (size_t)t * (N_BATCH * N_NEUR) + (size_t)b * N_NEUR + n;
        out[o]          = zs;
        out[o + PL]     = new_v;
        out[o + 2 * PL] = thr;
        out[o + 3 * PL] = v_sc;

        v = new_v; a = new_a; lsd = new_lsd; z = zs;

        __syncthreads();
        unsigned long long wm = __ballot(zs != 0.f);
        if (lane == 0) cnt4[wid] = __popcll(wm);
        if (zs != 0.f) {
            int pos = __popcll(wm & ((1ull << lane) - 1ull));
            act[wid * 64 + pos] = n;
        }
        if (!USE_XW && (t + 1 < T_STEPS))
            xsh[n] = xin[((size_t)b * T_STEPS + t + 1) * N_IN + n];
        __syncthreads();
    }
}

// ---------------------------------------------------------------------------
extern "C" void kernel_launch(void* const* d_in, const int* in_sizes, int n_in,
                              void* d_out, int out_size, void* d_ws, size_t ws_size,
                              hipStream_t stream) {
    const float* x     = (const float*)d_in[0];
    const float* w_in  = (const float*)d_in[1];
    const float* w_rec = (const float*)d_in[2];
    const float* z0    = (const float*)d_in[3];
    const float* v0    = (const float*)d_in[4];
    const float* a0    = (const float*)d_in[5];
    const float* lsd0  = (const float*)d_in[6];
    float* out = (float*)d_out;

    const size_t xw_bytes = (size_t)N_BATCH * T_STEPS * N_NEUR * sizeof(float);
    const size_t wz_bytes = (size_t)257 * 256 * sizeof(float);

    if (ws_size >= xw_bytes + wz_bytes) {
        float* xw = (float*)d_ws;
        float* wz = (float*)((char*)d_ws + xw_bytes);
        prep_wrec_kernel<<<257, 256, 0, stream>>>(w_rec, wz);
        dim3 grid(500, 2, 1);
        xw_gemm4_kernel<<<grid, 256, 0, stream>>>(x, w_in, xw);
        lsnn_scan7_kernel<<<N_BATCH, 256, 0, stream>>>(
            xw, wz, z0, v0, a0, lsd0, out);
    } else if (ws_size >= xw_bytes) {
        float* xw = (float*)d_ws;
        dim3 grid(500, 2, 1);
        xw_gemm4_kernel<<<grid, 256, 0, stream>>>(x, w_in, xw);
        lsnn_scan_kernel<true><<<N_BATCH, 256, 0, stream>>>(
            xw, nullptr, w_rec, z0, v0, a0, lsd0, out);
    } else {
        lsnn_scan_kernel<false><<<N_BATCH, 256, 0, stream>>>(
            x, w_in, w_rec, z0, v0, a0, lsd0, out);
    }
}

// Round 5
// 793.888 us; speedup vs baseline: 1.5333x; 1.1839x over previous
//
#include <hip/hip_runtime.h>

#define T_STEPS 500
#define N_NEUR  256
#define N_IN    256
#define N_BATCH 128

// Bs gap swizzle: insert a 4-float gap every 16 floats. Keeps any aligned
// 8-float block contiguous (float4/b128 still work) while spreading the 16
// lanes' 32B-strided reads across banks (<=2-way, which is free).
#define BPOS(c) ((c) + (((c) >> 4) << 2))

// ---------------------------------------------------------------------------
// Kernel 1 (v5): XW = X @ W_in  (M=64000, K=256, N=256), fp32 vector GEMM.
// 128x128 tile, 8x8 acc/thread, BK=16 DOUBLE-BUFFERED LDS: one barrier per
// K-tile (16 total vs 32). Per iteration: prefetch tile i+1 into regs (VMEM
// latency hides under the ~2000-cyc compute), compute from buf[cur], ds_write
// tile i+1 into buf[cur^1], barrier. WAR is safe: iter i+1 writes buf[cur]
// only after the barrier that ends iter i (whose reads were from buf[cur]).
// Per-output accumulation order unchanged (k0 asc, kk asc) -> bit-identical C.
// NO min-waves launch_bounds (R3 lesson: it spills the 64-reg accumulator).
// ---------------------------------------------------------------------------
__global__ __launch_bounds__(256) void xw_gemm5_kernel(
    const float* __restrict__ A,   // [M,256]
    const float* __restrict__ W,   // [256,256]
    float* __restrict__ C)         // [M,256]
{
    __shared__ float As[2][16][132];
    __shared__ float Bs[2][16][160];   // BPOS(127)=155 max extent, pad to 160
    const int tid = threadIdx.x;
    const int bm  = blockIdx.x;    // 0..499
    const int bn  = blockIdx.y;    // 0..1
    const int ty  = tid >> 4;      // 0..15
    const int tx  = tid & 15;      // 0..15
    const int arow  = tid >> 1;          // 0..127
    const int akoff = (tid & 1) * 8;     // 0 or 8
    const int brow  = tid >> 4;          // 0..15
    const int bcol  = (tid & 15) * 8;    // 0..120
    const float* Ab = A + (size_t)bm * 128 * 256;

    float acc[8][8];
#pragma unroll
    for (int i = 0; i < 8; ++i)
#pragma unroll
        for (int j = 0; j < 8; ++j) acc[i][j] = 0.f;

    // ---- stage tile 0 into buffer 0 ---------------------------------------
    {
        float4 av0 = *(const float4*)(Ab + (size_t)arow * 256 + akoff);
        float4 av1 = *(const float4*)(Ab + (size_t)arow * 256 + akoff + 4);
        float4 bv0 = *(const float4*)(W + (size_t)brow * 256 + bn * 128 + bcol);
        float4 bv1 = *(const float4*)(W + (size_t)brow * 256 + bn * 128 + bcol + 4);
        As[0][akoff + 0][arow] = av0.x; As[0][akoff + 1][arow] = av0.y;
        As[0][akoff + 2][arow] = av0.z; As[0][akoff + 3][arow] = av0.w;
        As[0][akoff + 4][arow] = av1.x; As[0][akoff + 5][arow] = av1.y;
        As[0][akoff + 6][arow] = av1.z; As[0][akoff + 7][arow] = av1.w;
        *(float4*)&Bs[0][brow][BPOS(bcol)]     = bv0;
        *(float4*)&Bs[0][brow][BPOS(bcol) + 4] = bv1;
    }
    __syncthreads();

    for (int it = 0; it < 16; ++it) {
        const int cur = it & 1;
        float4 av0, av1, bv0, bv1;
        const bool pf = (it + 1 < 16);
        if (pf) {                               // prefetch next tile into regs
            const int k0 = (it + 1) * 16;
            av0 = *(const float4*)(Ab + (size_t)arow * 256 + k0 + akoff);
            av1 = *(const float4*)(Ab + (size_t)arow * 256 + k0 + akoff + 4);
            bv0 = *(const float4*)(W + (size_t)(k0 + brow) * 256 + bn * 128 + bcol);
            bv1 = *(const float4*)(W + (size_t)(k0 + brow) * 256 + bn * 128 + bcol + 4);
        }
#pragma unroll
        for (int kk = 0; kk < 16; ++kk) {
            float a[8], b[8];
#pragma unroll
            for (int i = 0; i < 8; ++i) a[i] = As[cur][kk][ty * 8 + i];
#pragma unroll
            for (int j = 0; j < 8; ++j) b[j] = Bs[cur][kk][BPOS(tx * 8) + j];
#pragma unroll
            for (int i = 0; i < 8; ++i)
#pragma unroll
                for (int j = 0; j < 8; ++j)
                    acc[i][j] += a[i] * b[j];
        }
        if (pf) {                               // stage into the other buffer
            As[cur ^ 1][akoff + 0][arow] = av0.x; As[cur ^ 1][akoff + 1][arow] = av0.y;
            As[cur ^ 1][akoff + 2][arow] = av0.z; As[cur ^ 1][akoff + 3][arow] = av0.w;
            As[cur ^ 1][akoff + 4][arow] = av1.x; As[cur ^ 1][akoff + 5][arow] = av1.y;
            As[cur ^ 1][akoff + 6][arow] = av1.z; As[cur ^ 1][akoff + 7][arow] = av1.w;
            *(float4*)&Bs[cur ^ 1][brow][BPOS(bcol)]     = bv0;
            *(float4*)&Bs[cur ^ 1][brow][BPOS(bcol) + 4] = bv1;
        }
        __syncthreads();                        // ONE barrier per K-tile
    }

    const int crow = bm * 128 + ty * 8;
    const int ccol = bn * 128 + tx * 8;
#pragma unroll
    for (int i = 0; i < 8; ++i) {
        float4 v0 = make_float4(acc[i][0], acc[i][1], acc[i][2], acc[i][3]);
        float4 v1 = make_float4(acc[i][4], acc[i][5], acc[i][6], acc[i][7]);
        *(float4*)(C + (size_t)(crow + i) * 256 + ccol)     = v0;
        *(float4*)(C + (size_t)(crow + i) * 256 + ccol + 4) = v1;
    }
}

// ---------------------------------------------------------------------------
// Kernel 1b: build wrec_z = w_rec with zeroed diagonal + zero sentinel row 256.
// ---------------------------------------------------------------------------
__global__ void prep_wrec_kernel(const float* __restrict__ w_rec,
                                 float* __restrict__ wz)
{
    int i = blockIdx.x * 256 + threadIdx.x;   // 0 .. 257*256-1
    if (i < 256 * 256) {
        int r = i >> 8, c = i & 255;
        wz[i] = (r == c) ? 0.f : w_rec[i];
    } else {
        wz[i] = 0.f;                           // sentinel row 256
    }
}

// ---------------------------------------------------------------------------
// Kernel 2: dense register-resident recurrent scan — REVERT to the measured
// best (R1's scan3, 405 us, 4 waves/SIMD; the 4-way wave interleave per SIMD
// is what fills the serial per-step chain — all 256-thread variants pinned at
// ~2700 cyc/step regardless of vmem scheduling, R0/R3/R4 evidence).
// Only change vs R1: the in-loop __syncthreads is replaced by an LDS-only
// raw barrier (lgkmcnt(0)+s_barrier) — proven neutral-at-worst in R3's A/B;
// the only cross-wave dependency is the zsh publish (LDS).
// Numerics: identical to the R1-passing kernel -> bit-identical trajectory.
// ---------------------------------------------------------------------------
__global__ __launch_bounds__(1024) void lsnn_scan3_kernel(
    const float* __restrict__ xw,    // [B,T,N]
    const float* __restrict__ wz,    // [257,256] diag-zeroed (+ zero row)
    const float* __restrict__ z0, const float* __restrict__ v0,
    const float* __restrict__ a0, const float* __restrict__ lsd0,
    float* __restrict__ out)         // [4,T,B,N]
{
    const int b   = blockIdx.x;
    const int t0  = threadIdx.x;
    const int n   = t0 >> 2;          // neuron 0..255
    const int seg = t0 & 3;           // source-neuron segment 0..3

    __shared__ __align__(16) float zsh[2][4][72];  // [buf][seg row][k], padded

    const float dv   = (float)0.9512294245007140018;  // exp(-1/20) fp32
    const float omdv = 1.0f - dv;

    // ---- one-time: weight column slice into registers ---------------------
    float w[64];
    {
        const float* wc = wz + (size_t)seg * 64 * N_NEUR + n;
#pragma unroll
        for (int k = 0; k < 64; ++k) w[k] = wc[(size_t)k * N_NEUR];
    }

    const int bn = b * N_NEUR + n;
    float z   = z0[bn];
    float v   = v0[bn];
    float a   = a0[bn];
    float lsd = lsd0[bn];

    if (seg == 0) zsh[0][n >> 6][n & 63] = z;
    __syncthreads();

    float x_next = xw[((size_t)b * T_STEPS) * N_NEUR + n];
    const size_t PL = (size_t)T_STEPS * N_BATCH * N_NEUR;

    for (int t = 0; t < T_STEPS; ++t) {
        float x_cur = x_next;
        {
            int tn = (t + 1 < T_STEPS) ? t + 1 : t;
            x_next = xw[((size_t)b * T_STEPS + tn) * N_NEUR + n];
        }
        const int rb = t & 1;

        // ---- dense partial over this thread's 64 sources, ascending k -----
        const float* zr = &zsh[rb][seg][0];
        float p = 0.f;
#pragma unroll
        for (int k4 = 0; k4 < 16; ++k4) {
            float4 zv = *(const float4*)(zr + 4 * k4);   // broadcast read
            p = fmaf(zv.x, w[4 * k4 + 0], p);
            p = fmaf(zv.y, w[4 * k4 + 1], p);
            p = fmaf(zv.z, w[4 * k4 + 2], p);
            p = fmaf(zv.w, w[4 * k4 + 3], p);
        }

        // ---- quad reduce, exact order ((p0+p1)+p2)+p3 (DPP broadcasts) ----
        const int pi = __float_as_int(p);
        const float q0 = __int_as_float(__builtin_amdgcn_mov_dpp(pi, 0x00, 0xF, 0xF, true));
        const float q1 = __int_as_float(__builtin_amdgcn_mov_dpp(pi, 0x55, 0xF, 0xF, true));
        const float q2 = __int_as_float(__builtin_amdgcn_mov_dpp(pi, 0xAA, 0xF, 0xF, true));
        const float q3 = __int_as_float(__builtin_amdgcn_mov_dpp(pi, 0xFF, 0xF, 0xF, true));
        float i_rec = ((q0 + q1) + q2) + q3;

        // ---- neuron dynamics (verbatim from the passing kernel) -----------
        float i_in  = x_cur + i_rec;              // INTERNAL_CURRENT == 0
        float new_a = dv * a + omdv * z;
        float thr   = 0.03f + new_a * 1.8f;
        float new_v = dv * v + omdv * i_in - thr * z;
        float v_sc  = (new_v - thr) / thr;
        float zs    = (v_sc > 0.f) ? 1.f : 0.f;
        zs          = (lsd >= 2.0f) ? zs : 0.f;
        float new_lsd = (lsd + 1.f) * (1.f - zs);

        // ---- emit: each seg-thread stores its own output plane ------------
        size_t o = (size_t)t * (N_BATCH * N_NEUR) + (size_t)b * N_NEUR + n;
        float outv = (seg == 0) ? zs : (seg == 1) ? new_v
                   : (seg == 2) ? thr : v_sc;
        __builtin_nontemporal_store(outv, out + o + (size_t)seg * PL);

        v = new_v; a = new_a; lsd = new_lsd; z = zs;

        // ---- publish z for next step; LDS-only barrier --------------------
        if (seg == 0) zsh[rb ^ 1][n >> 6][n & 63] = zs;
        asm volatile("s_waitcnt lgkmcnt(0)" ::: "memory");
        __builtin_amdgcn_s_barrier();
        asm volatile("" ::: "memory");
    }
}

// ---------------------------------------------------------------------------
// Fallback scan (R1 version) — used only if ws_size is too small.
// ---------------------------------------------------------------------------
template <bool USE_XW>
__global__ __launch_bounds__(256) void lsnn_scan_kernel(
    const float* __restrict__ xin,
    const float* __restrict__ w_in,
    const float* __restrict__ w_rec,
    const float* __restrict__ z0, const float* __restrict__ v0,
    const float* __restrict__ a0, const float* __restrict__ lsd0,
    float* __restrict__ out)
{
    const int b    = blockIdx.x;
    const int n    = threadIdx.x;
    const int lane = n & 63;
    const int wid  = n >> 6;

    __shared__ int   cnt4[4];
    __shared__ int   act[256];
    __shared__ float xsh[256];

    const float dv   = (float)0.9512294245007140018;
    const float omdv = 1.0f - dv;

    const int base_bn = b * N_NEUR + n;
    float z   = z0[base_bn];
    float v   = v0[base_bn];
    float a   = a0[base_bn];
    float lsd = lsd0[base_bn];

    act[n] = 0;
    {
        unsigned long long wm = __ballot(z != 0.f);
        if (lane == 0) cnt4[wid] = __popcll(wm);
        if (z != 0.f) {
            int pos = __popcll(wm & ((1ull << lane) - 1ull));
            act[wid * 64 + pos] = n;
        }
        if (!USE_XW) xsh[n] = xin[((size_t)b * T_STEPS) * N_IN + n];
    }
    __syncthreads();

    float x_next = USE_XW ? xin[((size_t)b * T_STEPS) * N_NEUR + n] : 0.f;

    for (int t = 0; t < T_STEPS; ++t) {
        float x_cur = x_next;
        if (USE_XW) {
            int tn = (t + 1 < T_STEPS) ? t + 1 : t;
            x_next = xin[((size_t)b * T_STEPS + tn) * N_NEUR + n];
        }
        const int cs0 = cnt4[0], cs1 = cnt4[1], cs2 = cnt4[2], cs3 = cnt4[3];
        int mx = max(max(cs0, cs1), max(cs2, cs3));
        float r0 = 0.f, r1 = 0.f, r2 = 0.f, r3 = 0.f;
        for (int i0 = 0; i0 < mx; i0 += 8) {
            float wv[4][8];
            bool  ok[4][8];
#pragma unroll
            for (int sgi = 0; sgi < 4; ++sgi) {
                const int cs = (sgi == 0) ? cs0 : (sgi == 1) ? cs1 : (sgi == 2) ? cs2 : cs3;
#pragma unroll
                for (int j = 0; j < 8; ++j) {
                    int ii = i0 + j;
                    int m  = act[sgi * 64 + (ii < cs ? ii : 0)] & 255;
                    wv[sgi][j] = w_rec[m * N_NEUR + n];
                    ok[sgi][j] = (ii < cs) && (m != n);
                }
            }
#pragma unroll
            for (int j = 0; j < 8; ++j) r0 += ok[0][j] ? wv[0][j] : 0.f;
#pragma unroll
            for (int j = 0; j < 8; ++j) r1 += ok[1][j] ? wv[1][j] : 0.f;
#pragma unroll
            for (int j = 0; j < 8; ++j) r2 += ok[2][j] ? wv[2][j] : 0.f;
#pragma unroll
            for (int j = 0; j < 8; ++j) r3 += ok[3][j] ? wv[3][j] : 0.f;
        }
        float i_rec = ((r0 + r1) + r2) + r3;

        float xdot;
        if (USE_XW) {
            xdot = x_cur;
        } else {
            float sum = 0.f;
#pragma unroll 8
            for (int m = 0; m < N_IN; ++m) sum += xsh[m] * w_in[m * N_NEUR + n];
            xdot = sum;
        }
        float i_in = xdot + i_rec;

        float new_a = dv * a + omdv * z;
        float thr   = 0.03f + new_a * 1.8f;
        float new_v = dv * v + omdv * i_in - thr * z;
        float v_sc  = (new_v - thr) / thr;
        float zs    = (v_sc > 0.f) ? 1.f : 0.f;
        zs          = (lsd >= 2.0f) ? zs : 0.f;
        float new_lsd = (lsd + 1.f) * (1.f - zs);

        const size_t PL = (size_t)T_STEPS * N_BATCH * N_NEUR;
        size_t o = (size_t)t * (N_BATCH * N_NEUR) + (size_t)b * N_NEUR + n;
        out[o]          = zs;
        out[o + PL]     = new_v;
        out[o + 2 * PL] = thr;
        out[o + 3 * PL] = v_sc;

        v = new_v; a = new_a; lsd = new_lsd; z = zs;

        __syncthreads();
        unsigned long long wm = __ballot(zs != 0.f);
        if (lane == 0) cnt4[wid] = __popcll(wm);
        if (zs != 0.f) {
            int pos = __popcll(wm & ((1ull << lane) - 1ull));
            act[wid * 64 + pos] = n;
        }
        if (!USE_XW && (t + 1 < T_STEPS))
            xsh[n] = xin[((size_t)b * T_STEPS + t + 1) * N_IN + n];
        __syncthreads();
    }
}

// ---------------------------------------------------------------------------
extern "C" void kernel_launch(void* const* d_in, const int* in_sizes, int n_in,
                              void* d_out, int out_size, void* d_ws, size_t ws_size,
                              hipStream_t stream) {
    const float* x     = (const float*)d_in[0];
    const float* w_in  = (const float*)d_in[1];
    const float* w_rec = (const float*)d_in[2];
    const float* z0    = (const float*)d_in[3];
    const float* v0    = (const float*)d_in[4];
    const float* a0    = (const float*)d_in[5];
    const float* lsd0  = (const float*)d_in[6];
    float* out = (float*)d_out;

    const size_t xw_bytes = (size_t)N_BATCH * T_STEPS * N_NEUR * sizeof(float);
    const size_t wz_bytes = (size_t)257 * 256 * sizeof(float);

    if (ws_size >= xw_bytes + wz_bytes) {
        float* xw = (float*)d_ws;
        float* wz = (float*)((char*)d_ws + xw_bytes);
        prep_wrec_kernel<<<257, 256, 0, stream>>>(w_rec, wz);
        dim3 grid(500, 2, 1);
        xw_gemm5_kernel<<<grid, 256, 0, stream>>>(x, w_in, xw);
        lsnn_scan3_kernel<<<N_BATCH, 1024, 0, stream>>>(
            xw, wz, z0, v0, a0, lsd0, out);
    } else if (ws_size >= xw_bytes) {
        float* xw = (float*)d_ws;
        dim3 grid(500, 2, 1);
        xw_gemm5_kernel<<<grid, 256, 0, stream>>>(x, w_in, xw);
        lsnn_scan_kernel<true><<<N_BATCH, 256, 0, stream>>>(
            xw, nullptr, w_rec, z0, v0, a0, lsd0, out);
    } else {
        lsnn_scan_kernel<false><<<N_BATCH, 256, 0, stream>>>(
            x, w_in, w_rec, z0, v0, a0, lsd0, out);
    }
}

// Round 7
// 735.142 us; speedup vs baseline: 1.6558x; 1.0799x over previous
//
#include <hip/hip_runtime.h>

#define T_STEPS 500
#define N_NEUR  256
#define N_IN    256
#define N_BATCH 128

// Bs gap swizzle: insert a 4-float gap every 16 floats. Keeps any aligned
// 8-float block contiguous (float4/b128 still work) while spreading the 16
// lanes' 32B-strided reads across banks (<=2-way, which is free).
#define BPOS(c) ((c) + (((c) >> 4) << 2))

// ---------------------------------------------------------------------------
// Kernel 1 (v4): XW = X @ W_in  (M=64000, K=256, N=256), fp32 vector GEMM.
// Measured-best GEMM variant (R4: ~335 us). gemm5's dbuf was 384 -> reverted.
// Per-output accumulation order: k0 asc, kk asc, acc += a*b -> the chain all
// rounds have passed with.
// ---------------------------------------------------------------------------
__global__ __launch_bounds__(256) void xw_gemm4_kernel(
    const float* __restrict__ A,   // [M,256]
    const float* __restrict__ W,   // [256,256]
    float* __restrict__ C)         // [M,256]
{
    __shared__ float As[16][132];
    __shared__ float Bs[16][160];   // BPOS(127)=155 max extent, pad to 160
    const int tid = threadIdx.x;
    const int bm  = blockIdx.x;    // 0..499
    const int bn  = blockIdx.y;    // 0..1
    const int ty  = tid >> 4;      // 0..15
    const int tx  = tid & 15;      // 0..15
    const int arow  = tid >> 1;          // 0..127
    const int akoff = (tid & 1) * 8;     // 0 or 8
    const int brow  = tid >> 4;          // 0..15
    const int bcol  = (tid & 15) * 8;    // 0..120
    const float* Ab = A + (size_t)bm * 128 * 256;

    float acc[8][8];
#pragma unroll
    for (int i = 0; i < 8; ++i)
#pragma unroll
        for (int j = 0; j < 8; ++j) acc[i][j] = 0.f;

    // prologue: k0 = 0 tile into registers
    float4 av0 = *(const float4*)(Ab + (size_t)arow * 256 + akoff);
    float4 av1 = *(const float4*)(Ab + (size_t)arow * 256 + akoff + 4);
    float4 bv0 = *(const float4*)(W + (size_t)brow * 256 + bn * 128 + bcol);
    float4 bv1 = *(const float4*)(W + (size_t)brow * 256 + bn * 128 + bcol + 4);

    for (int k0 = 0; k0 < 256; k0 += 16) {
        __syncthreads();                      // prev compute done (no-op @k0=0)
        As[akoff + 0][arow] = av0.x; As[akoff + 1][arow] = av0.y;
        As[akoff + 2][arow] = av0.z; As[akoff + 3][arow] = av0.w;
        As[akoff + 4][arow] = av1.x; As[akoff + 5][arow] = av1.y;
        As[akoff + 6][arow] = av1.z; As[akoff + 7][arow] = av1.w;
        *(float4*)&Bs[brow][BPOS(bcol)]     = bv0;
        *(float4*)&Bs[brow][BPOS(bcol) + 4] = bv1;
        __syncthreads();
        if (k0 + 16 < 256) {                  // prefetch next tile into regs
            av0 = *(const float4*)(Ab + (size_t)arow * 256 + k0 + 16 + akoff);
            av1 = *(const float4*)(Ab + (size_t)arow * 256 + k0 + 16 + akoff + 4);
            bv0 = *(const float4*)(W + (size_t)(k0 + 16 + brow) * 256 + bn * 128 + bcol);
            bv1 = *(const float4*)(W + (size_t)(k0 + 16 + brow) * 256 + bn * 128 + bcol + 4);
        }
#pragma unroll
        for (int kk = 0; kk < 16; ++kk) {
            float a[8], b[8];
#pragma unroll
            for (int i = 0; i < 8; ++i) a[i] = As[kk][ty * 8 + i];
#pragma unroll
            for (int j = 0; j < 8; ++j) b[j] = Bs[kk][BPOS(tx * 8) + j];
#pragma unroll
            for (int i = 0; i < 8; ++i)
#pragma unroll
                for (int j = 0; j < 8; ++j)
                    acc[i][j] += a[i] * b[j];
        }
    }
    const int crow = bm * 128 + ty * 8;
    const int ccol = bn * 128 + tx * 8;
#pragma unroll
    for (int i = 0; i < 8; ++i) {
        float4 v0 = make_float4(acc[i][0], acc[i][1], acc[i][2], acc[i][3]);
        float4 v1 = make_float4(acc[i][4], acc[i][5], acc[i][6], acc[i][7]);
        *(float4*)(C + (size_t)(crow + i) * 256 + ccol)     = v0;
        *(float4*)(C + (size_t)(crow + i) * 256 + ccol + 4) = v1;
    }
}

// ---------------------------------------------------------------------------
// Kernel 1b: build wrec_z = w_rec with zeroed diagonal + zero sentinel row 256.
// ---------------------------------------------------------------------------
__global__ void prep_wrec_kernel(const float* __restrict__ w_rec,
                                 float* __restrict__ wz)
{
    int i = blockIdx.x * 256 + threadIdx.x;   // 0 .. 257*256-1
    if (i < 256 * 256) {
        int r = i >> 8, c = i & 255;
        wz[i] = (r == c) ? 0.f : w_rec[i];
    } else {
        wz[i] = 0.f;                           // sentinel row 256
    }
}

// ---------------------------------------------------------------------------
// Kernel 2 (v8): scan3 + TRUE register-resident weights.
//
// R1-R5 evidence: scan3 reported VGPR_Count=48 -> the declared w[64] was
// rematerialized; wz was re-read from L2 EVERY step (256 KB/block/step;
// 16 blocks/XCD / 4.3 TB/s L2 slice ~ 950 ns/step ~ the observed 820).
// The asm "+v" black-box below makes each loaded weight non-rematerializable,
// forcing ~64 live VGPRs (64 + ~48 working < 128/thread budget at the forced
// 4 waves/SIMD of a 1024-thread block -> no spill expected; WRITE_SIZE is the
// spill tripwire). No arithmetic change -> bit-identical trajectory.
// ---------------------------------------------------------------------------
__global__ __launch_bounds__(1024) void lsnn_scan8_kernel(
    const float* __restrict__ xw,    // [B,T,N]
    const float* __restrict__ wz,    // [257,256] diag-zeroed (+ zero row)
    const float* __restrict__ z0, const float* __restrict__ v0,
    const float* __restrict__ a0, const float* __restrict__ lsd0,
    float* __restrict__ out)         // [4,T,B,N]
{
    const int b   = blockIdx.x;
    const int t0  = threadIdx.x;
    const int n   = t0 >> 2;          // neuron 0..255
    const int seg = t0 & 3;           // source-neuron segment 0..3

    __shared__ __align__(16) float zsh[2][4][72];  // [buf][seg row][k], padded

    const float dv   = (float)0.9512294245007140018;  // exp(-1/20) fp32
    const float omdv = 1.0f - dv;

    // ---- one-time: weight column slice into registers, PINNED -------------
    float w[64];
    {
        const float* wc = wz + (size_t)seg * 64 * N_NEUR + n;
#pragma unroll
        for (int k = 0; k < 64; ++k) w[k] = wc[(size_t)k * N_NEUR];
#pragma unroll
        for (int k = 0; k < 64; ++k) asm volatile("" : "+v"(w[k]));  // pin
    }

    const int bn = b * N_NEUR + n;
    float z   = z0[bn];
    float v   = v0[bn];
    float a   = a0[bn];
    float lsd = lsd0[bn];

    if (seg == 0) zsh[0][n >> 6][n & 63] = z;
    __syncthreads();

    float x_next = xw[((size_t)b * T_STEPS) * N_NEUR + n];
    const size_t PL = (size_t)T_STEPS * N_BATCH * N_NEUR;

    for (int t = 0; t < T_STEPS; ++t) {
        float x_cur = x_next;
        {
            int tn = (t + 1 < T_STEPS) ? t + 1 : t;
            x_next = xw[((size_t)b * T_STEPS + tn) * N_NEUR + n];
        }
        const int rb = t & 1;

        // ---- dense partial over this thread's 64 sources, ascending k -----
        const float* zr = &zsh[rb][seg][0];
        float p = 0.f;
#pragma unroll
        for (int k4 = 0; k4 < 16; ++k4) {
            float4 zv = *(const float4*)(zr + 4 * k4);   // broadcast read
            p = fmaf(zv.x, w[4 * k4 + 0], p);
            p = fmaf(zv.y, w[4 * k4 + 1], p);
            p = fmaf(zv.z, w[4 * k4 + 2], p);
            p = fmaf(zv.w, w[4 * k4 + 3], p);
        }

        // ---- quad reduce, exact order ((p0+p1)+p2)+p3 (DPP broadcasts) ----
        const int pi = __float_as_int(p);
        const float q0 = __int_as_float(__builtin_amdgcn_mov_dpp(pi, 0x00, 0xF, 0xF, true));
        const float q1 = __int_as_float(__builtin_amdgcn_mov_dpp(pi, 0x55, 0xF, 0xF, true));
        const float q2 = __int_as_float(__builtin_amdgcn_mov_dpp(pi, 0xAA, 0xF, 0xF, true));
        const float q3 = __int_as_float(__builtin_amdgcn_mov_dpp(pi, 0xFF, 0xF, 0xF, true));
        float i_rec = ((q0 + q1) + q2) + q3;

        // ---- neuron dynamics (verbatim from the passing kernel) -----------
        float i_in  = x_cur + i_rec;              // INTERNAL_CURRENT == 0
        float new_a = dv * a + omdv * z;
        float thr   = 0.03f + new_a * 1.8f;
        float new_v = dv * v + omdv * i_in - thr * z;
        float v_sc  = (new_v - thr) / thr;
        float zs    = (v_sc > 0.f) ? 1.f : 0.f;
        zs          = (lsd >= 2.0f) ? zs : 0.f;
        float new_lsd = (lsd + 1.f) * (1.f - zs);

        // ---- emit: each seg-thread stores its own output plane ------------
        size_t o = (size_t)t * (N_BATCH * N_NEUR) + (size_t)b * N_NEUR + n;
        float outv = (seg == 0) ? zs : (seg == 1) ? new_v
                   : (seg == 2) ? thr : v_sc;
        __builtin_nontemporal_store(outv, out + o + (size_t)seg * PL);

        v = new_v; a = new_a; lsd = new_lsd; z = zs;

        // ---- publish z for next step; LDS-only barrier --------------------
        if (seg == 0) zsh[rb ^ 1][n >> 6][n & 63] = zs;
        asm volatile("s_waitcnt lgkmcnt(0)" ::: "memory");
        __builtin_amdgcn_s_barrier();
        asm volatile("" ::: "memory");
    }
}

// ---------------------------------------------------------------------------
// Fallback scan (R1 version) — used only if ws_size is too small.
// ---------------------------------------------------------------------------
template <bool USE_XW>
__global__ __launch_bounds__(256) void lsnn_scan_kernel(
    const float* __restrict__ xin,
    const float* __restrict__ w_in,
    const float* __restrict__ w_rec,
    const float* __restrict__ z0, const float* __restrict__ v0,
    const float* __restrict__ a0, const float* __restrict__ lsd0,
    float* __restrict__ out)
{
    const int b    = blockIdx.x;
    const int n    = threadIdx.x;
    const int lane = n & 63;
    const int wid  = n >> 6;

    __shared__ int   cnt4[4];
    __shared__ int   act[256];
    __shared__ float xsh[256];

    const float dv   = (float)0.9512294245007140018;
    const float omdv = 1.0f - dv;

    const int base_bn = b * N_NEUR + n;
    float z   = z0[base_bn];
    float v   = v0[base_bn];
    float a   = a0[base_bn];
    float lsd = lsd0[base_bn];

    act[n] = 0;
    {
        unsigned long long wm = __ballot(z != 0.f);
        if (lane == 0) cnt4[wid] = __popcll(wm);
        if (z != 0.f) {
            int pos = __popcll(wm & ((1ull << lane) - 1ull));
            act[wid * 64 + pos] = n;
        }
        if (!USE_XW) xsh[n] = xin[((size_t)b * T_STEPS) * N_IN + n];
    }
    __syncthreads();

    float x_next = USE_XW ? xin[((size_t)b * T_STEPS) * N_NEUR + n] : 0.f;

    for (int t = 0; t < T_STEPS; ++t) {
        float x_cur = x_next;
        if (USE_XW) {
            int tn = (t + 1 < T_STEPS) ? t + 1 : t;
            x_next = xin[((size_t)b * T_STEPS + tn) * N_NEUR + n];
        }
        const int cs0 = cnt4[0], cs1 = cnt4[1], cs2 = cnt4[2], cs3 = cnt4[3];
        int mx = max(max(cs0, cs1), max(cs2, cs3));
        float r0 = 0.f, r1 = 0.f, r2 = 0.f, r3 = 0.f;
        for (int i0 = 0; i0 < mx; i0 += 8) {
            float wv[4][8];
            bool  ok[4][8];
#pragma unroll
            for (int sgi = 0; sgi < 4; ++sgi) {
                const int cs = (sgi == 0) ? cs0 : (sgi == 1) ? cs1 : (sgi == 2) ? cs2 : cs3;
#pragma unroll
                for (int j = 0; j < 8; ++j) {
                    int ii = i0 + j;
                    int m  = act[sgi * 64 + (ii < cs ? ii : 0)] & 255;
                    wv[sgi][j] = w_rec[m * N_NEUR + n];
                    ok[sgi][j] = (ii < cs) && (m != n);
                }
            }
#pragma unroll
            for (int j = 0; j < 8; ++j) r0 += ok[0][j] ? wv[0][j] : 0.f;
#pragma unroll
            for (int j = 0; j < 8; ++j) r1 += ok[1][j] ? wv[1][j] : 0.f;
#pragma unroll
            for (int j = 0; j < 8; ++j) r2 += ok[2][j] ? wv[2][j] : 0.f;
#pragma unroll
            for (int j = 0; j < 8; ++j) r3 += ok[3][j] ? wv[3][j] : 0.f;
        }
        float i_rec = ((r0 + r1) + r2) + r3;

        float xdot;
        if (USE_XW) {
            xdot = x_cur;
        } else {
            float sum = 0.f;
#pragma unroll 8
            for (int m = 0; m < N_IN; ++m) sum += xsh[m] * w_in[m * N_NEUR + n];
            xdot = sum;
        }
        float i_in = xdot + i_rec;

        float new_a = dv * a + omdv * z;
        float thr   = 0.03f + new_a * 1.8f;
        float new_v = dv * v + omdv * i_in - thr * z;
        float v_sc  = (new_v - thr) / thr;
        float zs    = (v_sc > 0.f) ? 1.f : 0.f;
        zs          = (lsd >= 2.0f) ? zs : 0.f;
        float new_lsd = (lsd + 1.f) * (1.f - zs);

        const size_t PL = (size_t)T_STEPS * N_BATCH * N_NEUR;
        size_t o = (size_t)t * (N_BATCH * N_NEUR) + (size_t)b * N_NEUR + n;
        out[o]          = zs;
        out[o + PL]     = new_v;
        out[o + 2 * PL] = thr;
        out[o + 3 * PL] = v_sc;

        v = new_v; a = new_a; lsd = new_lsd; z = zs;

        __syncthreads();
        unsigned long long wm = __ballot(zs != 0.f);
        if (lane == 0) cnt4[wid] = __popcll(wm);
        if (zs != 0.f) {
            int pos = __popcll(wm & ((1ull << lane) - 1ull));
            act[wid * 64 + pos] = n;
        }
        if (!USE_XW && (t + 1 < T_STEPS))
            xsh[n] = xin[((size_t)b * T_STEPS + t + 1) * N_IN + n];
        __syncthreads();
    }
}

// ---------------------------------------------------------------------------
extern "C" void kernel_launch(void* const* d_in, const int* in_sizes, int n_in,
                              void* d_out, int out_size, void* d_ws, size_t ws_size,
                              hipStream_t stream) {
    const float* x     = (const float*)d_in[0];
    const float* w_in  = (const float*)d_in[1];
    const float* w_rec = (const float*)d_in[2];
    const float* z0    = (const float*)d_in[3];
    const float* v0    = (const float*)d_in[4];
    const float* a0    = (const float*)d_in[5];
    const float* lsd0  = (const float*)d_in[6];
    float* out = (float*)d_out;

    const size_t xw_bytes = (size_t)N_BATCH * T_STEPS * N_NEUR * sizeof(float);
    const size_t wz_bytes = (size_t)257 * 256 * sizeof(float);

    if (ws_size >= xw_bytes + wz_bytes) {
        float* xw = (float*)d_ws;
        float* wz = (float*)((char*)d_ws + xw_bytes);
        prep_wrec_kernel<<<257, 256, 0, stream>>>(w_rec, wz);
        dim3 grid(500, 2, 1);
        xw_gemm4_kernel<<<grid, 256, 0, stream>>>(x, w_in, xw);
        lsnn_scan8_kernel<<<N_BATCH, 1024, 0, stream>>>(
            xw, wz, z0, v0, a0, lsd0, out);
    } else if (ws_size >= xw_bytes) {
        float* xw = (float*)d_ws;
        dim3 grid(500, 2, 1);
        xw_gemm4_kernel<<<grid, 256, 0, stream>>>(x, w_in, xw);
        lsnn_scan_kernel<true><<<N_BATCH, 256, 0, stream>>>(
            xw, nullptr, w_rec, z0, v0, a0, lsd0, out);
    } else {
        lsnn_scan_kernel<false><<<N_BATCH, 256, 0, stream>>>(
            x, w_in, w_rec, z0, v0, a0, lsd0, out);
    }
}